// Round 1
// baseline (1139.667 us; speedup 1.0000x reference)
//
#include <hip/hip_runtime.h>
#include <math.h>

#define EEG_D 128
#define FMRI_D 64
#define BD 128
#define BDP 132      // padded stride (16B-aligned, breaks 16-way bank conflicts)
#define HD 32
#define NC 2
#define CD 64
#define CDP 68
#define TM 16        // rows per block
#define NT 128       // threads per block (= BD output channels)
#define EPS 1e-5f

__device__ __forceinline__ float gelu_exact(float x) {
    return 0.5f * x * (1.0f + erff(x * 0.70710678118654752f));
}

__global__ __launch_bounds__(NT) void fusion_kernel(
    const float* __restrict__ eeg, const float* __restrict__ fmri,
    const float* __restrict__ We, const float* __restrict__ be,
    const float* __restrict__ ge, const float* __restrict__ bge,
    const float* __restrict__ Wf, const float* __restrict__ bf,
    const float* __restrict__ gf, const float* __restrict__ bgf,
    const float* __restrict__ Wq, const float* __restrict__ bq,
    const float* __restrict__ Wk, const float* __restrict__ bk,
    const float* __restrict__ Wv, const float* __restrict__ bv,
    const float* __restrict__ Wo, const float* __restrict__ bo,
    const float* __restrict__ fusion_logits, const float* __restrict__ temperature,
    const float* __restrict__ Wc1, const float* __restrict__ bc1,
    const float* __restrict__ gc, const float* __restrict__ bgc,
    const float* __restrict__ Wc2, const float* __restrict__ bc2,
    float* __restrict__ out)
{
    __shared__ __align__(16) float s_ine[TM][EEG_D];
    __shared__ __align__(16) float s_inf[TM][FMRI_D];
    __shared__ __align__(16) float s_ep[TM][BDP];    // eeg proj (raw -> LN -> GELU)
    __shared__ __align__(16) float s_fp[TM][BDP];    // fmri proj
    __shared__ __align__(16) float s_ctx[TM][BDP];   // attention context
    __shared__ __align__(16) float s_fused[TM][BDP]; // fused features
    __shared__ __align__(16) float s_h[TM][CDP];     // classifier hidden
    __shared__ float s_redE[TM][2];
    __shared__ float s_redF[TM][2];

    const int tid = threadIdx.x;
    const int j = tid;                       // output channel for the 128-wide stages
    const long row0 = (long)blockIdx.x * TM;

    // ---- stage 0: load input tiles ----
    for (int i = tid; i < TM * EEG_D; i += NT)
        s_ine[i >> 7][i & 127] = eeg[row0 * EEG_D + i];
    for (int i = tid; i < TM * FMRI_D; i += NT)
        s_inf[i >> 6][i & 63] = fmri[row0 * FMRI_D + i];
    __syncthreads();

    // ---- stage 1: eeg raw projection (eeg @ We + be) ----
    {
        float acc[TM];
        float bias = be[j];
        #pragma unroll
        for (int r = 0; r < TM; ++r) acc[r] = bias;
        for (int k = 0; k < EEG_D; k += 4) {
            float w0 = We[(k + 0) * BD + j];
            float w1 = We[(k + 1) * BD + j];
            float w2 = We[(k + 2) * BD + j];
            float w3 = We[(k + 3) * BD + j];
            #pragma unroll
            for (int r = 0; r < TM; ++r) {
                float4 x = *(const float4*)&s_ine[r][k];
                acc[r] = fmaf(x.x, w0, acc[r]);
                acc[r] = fmaf(x.y, w1, acc[r]);
                acc[r] = fmaf(x.z, w2, acc[r]);
                acc[r] = fmaf(x.w, w3, acc[r]);
            }
        }
        #pragma unroll
        for (int r = 0; r < TM; ++r) s_ep[r][j] = acc[r];
    }
    // ---- stage 2: fmri raw projection (fmri @ Wf + bf) ----
    {
        float acc[TM];
        float bias = bf[j];
        #pragma unroll
        for (int r = 0; r < TM; ++r) acc[r] = bias;
        for (int k = 0; k < FMRI_D; k += 4) {
            float w0 = Wf[(k + 0) * BD + j];
            float w1 = Wf[(k + 1) * BD + j];
            float w2 = Wf[(k + 2) * BD + j];
            float w3 = Wf[(k + 3) * BD + j];
            #pragma unroll
            for (int r = 0; r < TM; ++r) {
                float4 x = *(const float4*)&s_inf[r][k];
                acc[r] = fmaf(x.x, w0, acc[r]);
                acc[r] = fmaf(x.y, w1, acc[r]);
                acc[r] = fmaf(x.z, w2, acc[r]);
                acc[r] = fmaf(x.w, w3, acc[r]);
            }
        }
        #pragma unroll
        for (int r = 0; r < TM; ++r) s_fp[r][j] = acc[r];
    }
    __syncthreads();

    // ---- LN stats: threads 0..15 -> eeg rows, 16..31 -> fmri rows ----
    if (tid < TM) {
        float sum = 0.0f, ss = 0.0f;
        for (int k = 0; k < BD; k += 4) {
            float4 x = *(const float4*)&s_ep[tid][k];
            sum += x.x + x.y + x.z + x.w;
            ss += x.x * x.x + x.y * x.y + x.z * x.z + x.w * x.w;
        }
        float mean = sum * (1.0f / BD);
        float var = ss * (1.0f / BD) - mean * mean;
        s_redE[tid][0] = mean;
        s_redE[tid][1] = rsqrtf(var + EPS);
    } else if (tid < 2 * TM) {
        int r = tid - TM;
        float sum = 0.0f, ss = 0.0f;
        for (int k = 0; k < BD; k += 4) {
            float4 x = *(const float4*)&s_fp[r][k];
            sum += x.x + x.y + x.z + x.w;
            ss += x.x * x.x + x.y * x.y + x.z * x.z + x.w * x.w;
        }
        float mean = sum * (1.0f / BD);
        float var = ss * (1.0f / BD) - mean * mean;
        s_redF[r][0] = mean;
        s_redF[r][1] = rsqrtf(var + EPS);
    }
    __syncthreads();

    // ---- apply LN + GELU to both projections ----
    {
        float g_e = ge[j], b_e = bge[j], g_f = gf[j], b_f = bgf[j];
        #pragma unroll
        for (int r = 0; r < TM; ++r) {
            float x = s_ep[r][j];
            x = (x - s_redE[r][0]) * s_redE[r][1] * g_e + b_e;
            s_ep[r][j] = gelu_exact(x);
            float y = s_fp[r][j];
            y = (y - s_redF[r][0]) * s_redF[r][1] * g_f + b_f;
            s_fp[r][j] = gelu_exact(y);
        }
    }
    __syncthreads();

    // ---- stage 3: q/k/v projections + 2-token attention ----
    {
        float qa[TM], kea[TM], kfa[TM], vea[TM], vfa[TM];
        float bq_ = bq[j], bk_ = bk[j], bv_ = bv[j];
        #pragma unroll
        for (int r = 0; r < TM; ++r) {
            qa[r] = bq_; kea[r] = bk_; kfa[r] = bk_; vea[r] = bv_; vfa[r] = bv_;
        }
        for (int k = 0; k < BD; k += 2) {
            float wq0 = Wq[(k + 0) * BD + j];
            float wq1 = Wq[(k + 1) * BD + j];
            float wk0 = Wk[(k + 0) * BD + j];
            float wk1 = Wk[(k + 1) * BD + j];
            float wv0 = Wv[(k + 0) * BD + j];
            float wv1 = Wv[(k + 1) * BD + j];
            #pragma unroll
            for (int r = 0; r < TM; ++r) {
                float2 e = *(const float2*)&s_ep[r][k];
                float2 f = *(const float2*)&s_fp[r][k];
                qa[r]  = fmaf(e.x, wq0, qa[r]);  qa[r]  = fmaf(e.y, wq1, qa[r]);
                kea[r] = fmaf(e.x, wk0, kea[r]); kea[r] = fmaf(e.y, wk1, kea[r]);
                kfa[r] = fmaf(f.x, wk0, kfa[r]); kfa[r] = fmaf(f.y, wk1, kfa[r]);
                vea[r] = fmaf(e.x, wv0, vea[r]); vea[r] = fmaf(e.y, wv1, vea[r]);
                vfa[r] = fmaf(f.x, wv0, vfa[r]); vfa[r] = fmaf(f.y, wv1, vfa[r]);
            }
        }
        const float scale = 0.17677669529663687f; // 1/sqrt(32)
        #pragma unroll
        for (int r = 0; r < TM; ++r) {
            float p0 = qa[r] * kea[r];
            float p1 = qa[r] * kfa[r];
            // reduce over the 32-lane head group (head = j>>5)
            #pragma unroll
            for (int m = 1; m <= 16; m <<= 1) {
                p0 += __shfl_xor(p0, m, 64);
                p1 += __shfl_xor(p1, m, 64);
            }
            float s0 = p0 * scale, s1 = p1 * scale;
            float mx = fmaxf(s0, s1);
            float e0 = expf(s0 - mx), e1 = expf(s1 - mx);
            float inv = 1.0f / (e0 + e1);
            s_ctx[r][j] = (e0 * vea[r] + e1 * vfa[r]) * inv;
        }
    }
    __syncthreads();

    // ---- stage 4: output projection (ctx @ Wo + bo) + learned fusion ----
    {
        float acc[TM];
        float bias = bo[j];
        #pragma unroll
        for (int r = 0; r < TM; ++r) acc[r] = bias;
        for (int k = 0; k < BD; k += 4) {
            float w0 = Wo[(k + 0) * BD + j];
            float w1 = Wo[(k + 1) * BD + j];
            float w2 = Wo[(k + 2) * BD + j];
            float w3 = Wo[(k + 3) * BD + j];
            #pragma unroll
            for (int r = 0; r < TM; ++r) {
                float4 x = *(const float4*)&s_ctx[r][k];
                acc[r] = fmaf(x.x, w0, acc[r]);
                acc[r] = fmaf(x.y, w1, acc[r]);
                acc[r] = fmaf(x.z, w2, acc[r]);
                acc[r] = fmaf(x.w, w3, acc[r]);
            }
        }
        float t = temperature[0];
        float l0 = fusion_logits[0] / t, l1 = fusion_logits[1] / t;
        float mx = fmaxf(l0, l1);
        float e0 = expf(l0 - mx), e1 = expf(l1 - mx);
        float w0f = e0 / (e0 + e1), w1f = e1 / (e0 + e1);
        #pragma unroll
        for (int r = 0; r < TM; ++r)
            s_fused[r][j] = w0f * acc[r] + w1f * s_fp[r][j];
    }
    __syncthreads();

    // ---- stage 5: classifier hidden (fused @ Wc1 + bc1), LN, ReLU ----
    if (tid < CD) {
        float acc[TM];
        float bias = bc1[j];
        #pragma unroll
        for (int r = 0; r < TM; ++r) acc[r] = bias;
        for (int k = 0; k < BD; k += 4) {
            float w0 = Wc1[(k + 0) * CD + j];
            float w1 = Wc1[(k + 1) * CD + j];
            float w2 = Wc1[(k + 2) * CD + j];
            float w3 = Wc1[(k + 3) * CD + j];
            #pragma unroll
            for (int r = 0; r < TM; ++r) {
                float4 x = *(const float4*)&s_fused[r][k];
                acc[r] = fmaf(x.x, w0, acc[r]);
                acc[r] = fmaf(x.y, w1, acc[r]);
                acc[r] = fmaf(x.z, w2, acc[r]);
                acc[r] = fmaf(x.w, w3, acc[r]);
            }
        }
        #pragma unroll
        for (int r = 0; r < TM; ++r) s_h[r][j] = acc[r];
    }
    __syncthreads();
    if (tid < TM) {
        float sum = 0.0f, ss = 0.0f;
        for (int k = 0; k < CD; k += 4) {
            float4 x = *(const float4*)&s_h[tid][k];
            sum += x.x + x.y + x.z + x.w;
            ss += x.x * x.x + x.y * x.y + x.z * x.z + x.w * x.w;
        }
        float mean = sum * (1.0f / CD);
        float var = ss * (1.0f / CD) - mean * mean;
        s_redE[tid][0] = mean;
        s_redE[tid][1] = rsqrtf(var + EPS);
    }
    __syncthreads();
    if (tid < CD) {
        float g = gc[j], b = bgc[j];
        #pragma unroll
        for (int r = 0; r < TM; ++r) {
            float x = s_h[r][j];
            x = (x - s_redE[r][0]) * s_redE[r][1] * g + b;
            s_h[r][j] = fmaxf(x, 0.0f);
        }
    }
    __syncthreads();

    // ---- stage 6: logits (h @ Wc2 + bc2) ----
    if (tid < TM * NC) {
        int r = tid >> 1, c = tid & 1;
        float acc = bc2[c];
        for (int k = 0; k < CD; ++k)
            acc = fmaf(s_h[r][k], Wc2[k * NC + c], acc);
        out[(row0 + r) * NC + c] = acc;
    }
}

extern "C" void kernel_launch(void* const* d_in, const int* in_sizes, int n_in,
                              void* d_out, int out_size, void* d_ws, size_t ws_size,
                              hipStream_t stream) {
    const float* eeg  = (const float*)d_in[0];
    const float* fmri = (const float*)d_in[1];
    const float* We   = (const float*)d_in[2];
    const float* be   = (const float*)d_in[3];
    const float* ge   = (const float*)d_in[4];
    const float* bge  = (const float*)d_in[5];
    const float* Wf   = (const float*)d_in[6];
    const float* bf   = (const float*)d_in[7];
    const float* gf   = (const float*)d_in[8];
    const float* bgf  = (const float*)d_in[9];
    const float* Wq   = (const float*)d_in[10];
    const float* bq   = (const float*)d_in[11];
    const float* Wk   = (const float*)d_in[12];
    const float* bk   = (const float*)d_in[13];
    const float* Wv   = (const float*)d_in[14];
    const float* bv   = (const float*)d_in[15];
    const float* Wo   = (const float*)d_in[16];
    const float* bo   = (const float*)d_in[17];
    const float* fl   = (const float*)d_in[18];
    const float* temp = (const float*)d_in[19];
    const float* Wc1  = (const float*)d_in[20];
    const float* bc1  = (const float*)d_in[21];
    const float* gc   = (const float*)d_in[22];
    const float* bgc  = (const float*)d_in[23];
    const float* Wc2  = (const float*)d_in[24];
    const float* bc2  = (const float*)d_in[25];
    float* out = (float*)d_out;

    int B = in_sizes[0] / EEG_D;   // 131072
    int grid = B / TM;             // 8192
    hipLaunchKernelGGL(fusion_kernel, dim3(grid), dim3(NT), 0, stream,
                       eeg, fmri, We, be, ge, bge, Wf, bf, gf, bgf,
                       Wq, bq, Wk, bk, Wv, bv, Wo, bo, fl, temp,
                       Wc1, bc1, gc, bgc, Wc2, bc2, out);
}

// Round 2
// 364.076 us; speedup vs baseline: 3.1303x; 3.1303x over previous
//
#include <hip/hip_runtime.h>
#include <math.h>

#define EEG_D 128
#define FMRI_D 64
#define BD 128
#define CD 64
#define NC 2
#define TM 16          // rows per block
#define NT 256         // threads per block (4 waves)
#define EPS 1e-5f
#define SCALE 0.17677669529663687f   // 1/sqrt(32)

// packed bf16 weight offsets in d_ws (ushort units)
#define OFF_We  0
#define OFF_Wf  16384
#define OFF_Wq  24576
#define OFF_Wk  40960
#define OFF_Wv  57344
#define OFF_Wo  73728
#define OFF_Wc1 90112
#define PACK_TOTAL 98304

typedef __bf16 bf16x8 __attribute__((ext_vector_type(8)));
typedef float f32x4 __attribute__((ext_vector_type(4)));
typedef unsigned short ushort_t;

__device__ __forceinline__ unsigned short f2bf(float x) {
    unsigned u = __builtin_bit_cast(unsigned, x);
    u = (u + 0x7fffu + ((u >> 16) & 1u)) >> 16;   // RNE
    return (unsigned short)u;
}

__device__ __forceinline__ float gelu_exact(float x) {
    return 0.5f * x * (1.0f + erff(x * 0.70710678118654752f));
}

// ---------------- weight pack kernel ----------------
// packs fp32 W[K][N] (row-major) into bf16 B-fragment order:
// element at ((ntile*KS + kstep)*64 + lane)*8 + j  holds  W[kstep*32 + (lane>>4)*8 + j][ntile*16 + (lane&15)]
__global__ __launch_bounds__(256) void pack_all(
    const float* __restrict__ We, const float* __restrict__ Wf,
    const float* __restrict__ Wq, const float* __restrict__ Wk,
    const float* __restrict__ Wv, const float* __restrict__ Wo,
    const float* __restrict__ Wc1, ushort_t* __restrict__ ws)
{
    int o = blockIdx.x * 256 + threadIdx.x;
    if (o >= PACK_TOTAL) return;
    const float* W; int K, N, base;
    if (o < OFF_Wf)        { W = We;  K = 128; N = 128; base = OFF_We; }
    else if (o < OFF_Wq)   { W = Wf;  K = 64;  N = 128; base = OFF_Wf; }
    else if (o < OFF_Wk)   { W = Wq;  K = 128; N = 128; base = OFF_Wq; }
    else if (o < OFF_Wv)   { W = Wk;  K = 128; N = 128; base = OFF_Wk; }
    else if (o < OFF_Wo)   { W = Wv;  K = 128; N = 128; base = OFF_Wv; }
    else if (o < OFF_Wc1)  { W = Wo;  K = 128; N = 128; base = OFF_Wo; }
    else                   { W = Wc1; K = 128; N = 64;  base = OFF_Wc1; }
    int e = o - base;
    int j = e & 7, l = (e >> 3) & 63, rest = e >> 9;
    int KS = K >> 5;
    int s = rest % KS, t = rest / KS;
    int k = s * 32 + ((l >> 4) << 3) + j;
    int n = (t << 4) + (l & 15);
    ws[o] = f2bf(W[k * N + n]);
}

// ---------------- fused MFMA GEMM helper ----------------
// A (bf16 LDS rows, 16 rows x K, stride strideA ushorts, +pad), W packed bf16,
// computes C[16][N-slice] = A@W + bias for ntn n-tiles starting at nt0.
// C layout per MFMA: row = quad*4+reg, col = lane&15 (within n-tile).
__device__ __forceinline__ void gemm16(
    const ushort_t* Abase, int strideA, const ushort_t* __restrict__ Wp,
    int KS, int nt0, int ntn, float* Cbase, int strideC,
    const float* __restrict__ bias, int lane)
{
    const int quad = lane >> 4, l16 = lane & 15;
    const ushort_t* aptr = Abase + l16 * strideA + quad * 8;
    for (int t = 0; t < ntn; ++t) {
        int nt = nt0 + t;
        int col = (nt << 4) + l16;
        float bcol = bias[col];
        f32x4 acc = {bcol, bcol, bcol, bcol};
        const ushort_t* bptr = Wp + ((nt * KS) * 64 + lane) * 8;
        for (int ks = 0; ks < KS; ++ks) {
            bf16x8 a = *(const bf16x8*)(aptr + ks * 32);
            bf16x8 b = *(const bf16x8*)(bptr + ks * 512);
            acc = __builtin_amdgcn_mfma_f32_16x16x32_bf16(a, b, acc, 0, 0, 0);
        }
        #pragma unroll
        for (int r = 0; r < 4; ++r)
            Cbase[(quad * 4 + r) * strideC + col] = acc[r];
    }
}

// ---------------- main fused kernel ----------------
__global__ __launch_bounds__(NT) void fusion_mfma(
    const float* __restrict__ eeg, const float* __restrict__ fmri,
    const float* __restrict__ be, const float* __restrict__ ge, const float* __restrict__ bge,
    const float* __restrict__ bf, const float* __restrict__ gf, const float* __restrict__ bgf,
    const float* __restrict__ bq, const float* __restrict__ bk, const float* __restrict__ bv,
    const float* __restrict__ bo,
    const float* __restrict__ fusion_logits, const float* __restrict__ temperature,
    const float* __restrict__ bc1, const float* __restrict__ gc, const float* __restrict__ bgc,
    const float* __restrict__ Wc2, const float* __restrict__ bc2,
    const ushort_t* __restrict__ ws, float* __restrict__ out)
{
    __shared__ __align__(16) ushort_t A_e[TM][136];   // eeg input bf16 A-rows
    __shared__ __align__(16) ushort_t A_f[TM][72];    // fmri input bf16 A-rows
    __shared__ __align__(16) ushort_t EP_A[TM][136];  // eeg_p bf16 (later: ctx)
    __shared__ __align__(16) ushort_t FP_A[TM][136];  // fmri_p bf16 (later: fused)
    __shared__ __align__(16) float FPf[TM][132];      // fmri_p fp32 (fusion)
    __shared__ __align__(16) float C32[TM][132];      // generic GEMM output
    __shared__ __align__(16) float Q32[TM][132];      // q / partial-ctx
    __shared__ float s_s0[TM][4], s_s1[TM][4];
    __shared__ float s_a0[TM][4], s_a1[TM][4];
    __shared__ float s_redE[TM][2], s_redF[TM][2];

    const int tid = threadIdx.x;
    const int wave = tid >> 6, lane = tid & 63;
    const long row0 = (long)blockIdx.x * TM;

    // ---- stage inputs -> bf16 A-form LDS ----
    {
        const float* src = eeg + row0 * EEG_D;
        #pragma unroll
        for (int i = 0; i < 2; ++i) {
            int idx4 = tid + i * 256;            // 512 float4s total
            int r = idx4 >> 5;                   // 32 float4 per row
            int k = (idx4 & 31) << 2;
            float4 x = *(const float4*)(src + ((long)idx4 << 2));
            ushort_t* dst = &A_e[r][k];
            dst[0] = f2bf(x.x); dst[1] = f2bf(x.y); dst[2] = f2bf(x.z); dst[3] = f2bf(x.w);
        }
        const float* srcf = fmri + row0 * FMRI_D;
        int idx4 = tid;                          // 256 float4s total
        int r = idx4 >> 4;
        int k = (idx4 & 15) << 2;
        float4 x = *(const float4*)(srcf + ((long)idx4 << 2));
        ushort_t* dst = &A_f[r][k];
        dst[0] = f2bf(x.x); dst[1] = f2bf(x.y); dst[2] = f2bf(x.z); dst[3] = f2bf(x.w);
    }
    __syncthreads();

    // ---- raw projections: eeg@We -> C32, fmri@Wf -> Q32 ----
    gemm16(&A_e[0][0], 136, ws + OFF_We, 4, wave * 2, 2, &C32[0][0], 132, be, lane);
    gemm16(&A_f[0][0], 72,  ws + OFF_Wf, 2, wave * 2, 2, &Q32[0][0], 132, bf, lane);
    __syncthreads();

    // ---- LN stats ----
    if (tid < TM) {
        float sum = 0.f, ss = 0.f;
        for (int k = 0; k < BD; k += 4) {
            float4 x = *(const float4*)&C32[tid][k];
            sum += x.x + x.y + x.z + x.w;
            ss += x.x * x.x + x.y * x.y + x.z * x.z + x.w * x.w;
        }
        float mean = sum * (1.0f / BD);
        float var = ss * (1.0f / BD) - mean * mean;
        s_redE[tid][0] = mean; s_redE[tid][1] = rsqrtf(var + EPS);
    } else if (tid < 2 * TM) {
        int r = tid - TM;
        float sum = 0.f, ss = 0.f;
        for (int k = 0; k < BD; k += 4) {
            float4 x = *(const float4*)&Q32[r][k];
            sum += x.x + x.y + x.z + x.w;
            ss += x.x * x.x + x.y * x.y + x.z * x.z + x.w * x.w;
        }
        float mean = sum * (1.0f / BD);
        float var = ss * (1.0f / BD) - mean * mean;
        s_redF[r][0] = mean; s_redF[r][1] = rsqrtf(var + EPS);
    }
    __syncthreads();

    // ---- LN + GELU -> EP_A (bf16), FP_A (bf16) + FPf (fp32) ----
    {
        int jj = tid & 127, rb = tid >> 7;
        float g_e = ge[jj], b_e = bge[jj], g_f = gf[jj], b_f = bgf[jj];
        #pragma unroll
        for (int i = 0; i < 8; ++i) {
            int r = rb + i * 2;
            float x = C32[r][jj];
            x = (x - s_redE[r][0]) * s_redE[r][1] * g_e + b_e;
            EP_A[r][jj] = f2bf(gelu_exact(x));
            float y = Q32[r][jj];
            y = (y - s_redF[r][0]) * s_redF[r][1] * g_f + b_f;
            y = gelu_exact(y);
            FP_A[r][jj] = f2bf(y);
            FPf[r][jj] = y;
        }
    }
    __syncthreads();

    // ---- q -> Q32, k_e -> C32 ----
    gemm16(&EP_A[0][0], 136, ws + OFF_Wq, 4, wave * 2, 2, &Q32[0][0], 132, bq, lane);
    gemm16(&EP_A[0][0], 136, ws + OFF_Wk, 4, wave * 2, 2, &C32[0][0], 132, bk, lane);
    __syncthreads();

    // ---- scores s0 = q.k_e per (row, head) ----
    if (tid < 128) {
        int j = tid;
        for (int r = 0; r < TM; ++r) {
            float p = Q32[r][j] * C32[r][j];
            #pragma unroll
            for (int m = 1; m <= 16; m <<= 1) p += __shfl_xor(p, m, 64);
            if ((j & 31) == 0) s_s0[r][j >> 5] = p * SCALE;
        }
    }
    __syncthreads();

    // ---- k_f -> C32 ----
    gemm16(&FP_A[0][0], 136, ws + OFF_Wk, 4, wave * 2, 2, &C32[0][0], 132, bk, lane);
    __syncthreads();

    // ---- scores s1 = q.k_f ----
    if (tid < 128) {
        int j = tid;
        for (int r = 0; r < TM; ++r) {
            float p = Q32[r][j] * C32[r][j];
            #pragma unroll
            for (int m = 1; m <= 16; m <<= 1) p += __shfl_xor(p, m, 64);
            if ((j & 31) == 0) s_s1[r][j >> 5] = p * SCALE;
        }
    }
    __syncthreads();

    // ---- softmax over the 2 tokens ----
    if (tid < 64) {
        int r = tid >> 2, h = tid & 3;
        float s0 = s_s0[r][h], s1 = s_s1[r][h];
        float mx = fmaxf(s0, s1);
        float e0 = expf(s0 - mx), e1 = expf(s1 - mx);
        float inv = 1.0f / (e0 + e1);
        s_a0[r][h] = e0 * inv; s_a1[r][h] = e1 * inv;
    }
    __syncthreads();

    // ---- v_e -> C32; partial ctx = a0*v_e -> Q32 (q dead) ----
    gemm16(&EP_A[0][0], 136, ws + OFF_Wv, 4, wave * 2, 2, &C32[0][0], 132, bv, lane);
    __syncthreads();
    {
        int jj = tid & 127, h = jj >> 5, rb = tid >> 7;
        #pragma unroll
        for (int i = 0; i < 8; ++i) {
            int r = rb + i * 2;
            Q32[r][jj] = s_a0[r][h] * C32[r][jj];
        }
    }
    __syncthreads();

    // ---- v_f -> C32; ctx = Q32 + a1*v_f -> EP_A bf16 (ep dead) ----
    gemm16(&FP_A[0][0], 136, ws + OFF_Wv, 4, wave * 2, 2, &C32[0][0], 132, bv, lane);
    __syncthreads();
    {
        int jj = tid & 127, h = jj >> 5, rb = tid >> 7;
        #pragma unroll
        for (int i = 0; i < 8; ++i) {
            int r = rb + i * 2;
            float c = Q32[r][jj] + s_a1[r][h] * C32[r][jj];
            EP_A[r][jj] = f2bf(c);
        }
    }
    __syncthreads();

    // ---- eeg_enh = ctx@Wo + bo -> C32; fusion -> FP_A bf16 (fp dead) ----
    gemm16(&EP_A[0][0], 136, ws + OFF_Wo, 4, wave * 2, 2, &C32[0][0], 132, bo, lane);
    __syncthreads();
    {
        float t = temperature[0];
        float l0 = fusion_logits[0] / t, l1 = fusion_logits[1] / t;
        float mx = fmaxf(l0, l1);
        float e0 = expf(l0 - mx), e1 = expf(l1 - mx);
        float w0 = e0 / (e0 + e1), w1 = e1 / (e0 + e1);
        int jj = tid & 127, rb = tid >> 7;
        #pragma unroll
        for (int i = 0; i < 8; ++i) {
            int r = rb + i * 2;
            float fu = w0 * C32[r][jj] + w1 * FPf[r][jj];
            FP_A[r][jj] = f2bf(fu);
        }
    }
    __syncthreads();

    // ---- classifier hidden: fused@Wc1 + bc1 -> C32[:, 0:64] ----
    gemm16(&FP_A[0][0], 136, ws + OFF_Wc1, 4, wave, 1, &C32[0][0], 132, bc1, lane);
    __syncthreads();
    if (tid < TM) {
        float sum = 0.f, ss = 0.f;
        for (int k = 0; k < CD; k += 4) {
            float4 x = *(const float4*)&C32[tid][k];
            sum += x.x + x.y + x.z + x.w;
            ss += x.x * x.x + x.y * x.y + x.z * x.z + x.w * x.w;
        }
        float mean = sum * (1.0f / CD);
        float var = ss * (1.0f / CD) - mean * mean;
        s_redE[tid][0] = mean; s_redE[tid][1] = rsqrtf(var + EPS);
    }
    __syncthreads();
    {
        int jj = tid & 63, rb = tid >> 6;
        float g = gc[jj], b = bgc[jj];
        #pragma unroll
        for (int i = 0; i < 4; ++i) {
            int r = rb + i * 4;
            float x = C32[r][jj];
            x = (x - s_redE[r][0]) * s_redE[r][1] * g + b;
            C32[r][jj] = fmaxf(x, 0.0f);
        }
    }
    __syncthreads();

    // ---- logits ----
    if (tid < TM * NC) {
        int r = tid >> 1, c = tid & 1;
        float acc = bc2[c];
        for (int k = 0; k < CD; ++k)
            acc = fmaf(C32[r][k], Wc2[k * NC + c], acc);
        out[(row0 + r) * NC + c] = acc;
    }
}

extern "C" void kernel_launch(void* const* d_in, const int* in_sizes, int n_in,
                              void* d_out, int out_size, void* d_ws, size_t ws_size,
                              hipStream_t stream) {
    const float* eeg  = (const float*)d_in[0];
    const float* fmri = (const float*)d_in[1];
    const float* We   = (const float*)d_in[2];
    const float* be   = (const float*)d_in[3];
    const float* ge   = (const float*)d_in[4];
    const float* bge  = (const float*)d_in[5];
    const float* Wf   = (const float*)d_in[6];
    const float* bf   = (const float*)d_in[7];
    const float* gf   = (const float*)d_in[8];
    const float* bgf  = (const float*)d_in[9];
    const float* Wq   = (const float*)d_in[10];
    const float* bq   = (const float*)d_in[11];
    const float* Wk   = (const float*)d_in[12];
    const float* bk   = (const float*)d_in[13];
    const float* Wv   = (const float*)d_in[14];
    const float* bv   = (const float*)d_in[15];
    const float* Wo   = (const float*)d_in[16];
    const float* bo   = (const float*)d_in[17];
    const float* fl   = (const float*)d_in[18];
    const float* temp = (const float*)d_in[19];
    const float* Wc1  = (const float*)d_in[20];
    const float* bc1  = (const float*)d_in[21];
    const float* gc   = (const float*)d_in[22];
    const float* bgc  = (const float*)d_in[23];
    const float* Wc2  = (const float*)d_in[24];
    const float* bc2  = (const float*)d_in[25];
    float* out = (float*)d_out;
    ushort_t* ws = (ushort_t*)d_ws;

    // pack weights to bf16 B-fragment layout (runs every call; ws re-poisoned)
    hipLaunchKernelGGL(pack_all, dim3((PACK_TOTAL + 255) / 256), dim3(256), 0, stream,
                       We, Wf, Wq, Wk, Wv, Wo, Wc1, ws);

    int B = in_sizes[0] / EEG_D;   // 131072
    int grid = B / TM;             // 8192
    hipLaunchKernelGGL(fusion_mfma, dim3(grid), dim3(NT), 0, stream,
                       eeg, fmri, be, ge, bge, bf, gf, bgf,
                       bq, bk, bv, bo, fl, temp, bc1, gc, bgc, Wc2, bc2,
                       ws, out);
}